// Round 8
// baseline (8586.514 us; speedup 1.0000x reference)
//
#include <hip/hip_runtime.h>
#include <math.h>

#define N_NODES 10000
#define N_EDGES 320000
#define GRID 250
#define BLOCK 512
#define NPW 5            // nodes per wave
#define NPB 40           // nodes per block
#define ECAP 2048        // LDS edge cache (mean 1280/block, max ~1450)
#define GSIZE 25         // barrier tree: blocks per group
#define NGRP 10          // groups (GSIZE*NGRP == GRID)

// ---------------- cross-block store: agent-scope write-through (R5-proven) ----
__device__ __forceinline__ void ast(float* p, float v) {
    __hip_atomic_store(p, v, __ATOMIC_RELAXED, __HIP_MEMORY_SCOPE_AGENT);
}

// ---------------- tree grid barrier (monotonic counters, no resets) ----------
// Release: every thread drains its wave's WT stores (workgroup fence = vmcnt0),
// __syncthreads joins waves. Arrival: 25-way per-group counter, group leader
// bumps root, global-last release-stores gen=step+1. Acquire: buffer_inv.
__device__ __forceinline__ void gbar(int* bar, int step, int bid) {
    __builtin_amdgcn_fence(__ATOMIC_RELEASE, "workgroup");
    __syncthreads();
    if (threadIdx.x == 0) {
        int* gc   = bar + (bid / GSIZE) * 32;   // 128B apart
        int* root = bar + 512;
        int* gen  = bar + 544;
        int tgt = step + 1;
        int a = __hip_atomic_fetch_add(gc, 1, __ATOMIC_RELEASE, __HIP_MEMORY_SCOPE_AGENT);
        if (a == GSIZE * tgt - 1) {
            int r = __hip_atomic_fetch_add(root, 1, __ATOMIC_RELEASE, __HIP_MEMORY_SCOPE_AGENT);
            if (r == NGRP * tgt - 1)
                __hip_atomic_store(gen, tgt, __ATOMIC_RELEASE, __HIP_MEMORY_SCOPE_AGENT);
        }
        while (__hip_atomic_load(gen, __ATOMIC_RELAXED, __HIP_MEMORY_SCOPE_AGENT) < tgt)
            __builtin_amdgcn_s_sleep(2);
        __builtin_amdgcn_fence(__ATOMIC_ACQUIRE, "agent");  // buffer_inv (L1+L2)
    }
    __syncthreads();
}

// ---------------- setup kernels ----------------
__global__ void k_init(float* deg, int* cnt, int* fill, int* bar, int n) {
    int i = blockIdx.x * blockDim.x + threadIdx.x;
    if (i < n) { deg[i] = 0.f; cnt[i] = 0; fill[i] = 0; }
    if (i < 1024) bar[i] = 0;
}

__global__ void k_deg(const int* __restrict__ ei, const float* __restrict__ w,
                      float* deg, int E) {
    int e = blockIdx.x * blockDim.x + threadIdx.x;
    if (e < E) atomicAdd(&deg[ei[e]], w[e]);
}

__global__ void k_dis(float* deg, int n) {
    int i = blockIdx.x * blockDim.x + threadIdx.x;
    if (i < n) {
        float d = deg[i];
        deg[i] = (d > 0.f) ? (float)(1.0 / sqrt((double)d)) : 0.f;
    }
}

__global__ void k_norm(const int* __restrict__ ei, const float* __restrict__ w,
                       const float* __restrict__ dis, float* __restrict__ normw,
                       int* cnt, int E) {
    int e = blockIdx.x * blockDim.x + threadIdx.x;
    if (e < E) {
        int s = ei[e], d = ei[E + e];
        normw[e] = -dis[s] * w[e] * dis[d];
        atomicAdd(&cnt[d], 1);
    }
}

__global__ void k_scan(const int* __restrict__ cnt, int* __restrict__ rowptr, int n) {
    __shared__ int part[1024];
    const int PER = 10;
    int t = threadIdx.x;
    int base = t * PER;
    int local[PER];
    int s = 0;
    for (int j = 0; j < PER; j++) {
        int idx = base + j;
        int v = (idx < n) ? cnt[idx] : 0;
        local[j] = v; s += v;
    }
    part[t] = s;
    __syncthreads();
    for (int off = 1; off < 1024; off <<= 1) {
        int v = part[t];
        int u = (t >= off) ? part[t - off] : 0;
        __syncthreads();
        part[t] = v + u;
        __syncthreads();
    }
    int excl = (t > 0) ? part[t - 1] : 0;
    for (int j = 0; j < PER; j++) {
        int idx = base + j;
        if (idx < n) rowptr[idx] = excl;
        excl += local[j];
    }
    if (t == 1023) rowptr[n] = part[1023];
}

// pair CSR: {src byte-offset for stride-64 rows (src<<8), norm bits}
__global__ void k_fill(const int* __restrict__ ei, const float* __restrict__ normw,
                       const int* __restrict__ rowptr, int* fill,
                       int2* __restrict__ pr, int E) {
    int e = blockIdx.x * blockDim.x + threadIdx.x;
    if (e < E) {
        int d = ei[E + e];
        int pos = atomicAdd(&fill[d], 1);
        int idx = rowptr[d] + pos;
        pr[idx] = make_int2(ei[e] << 8, __float_as_int(normw[e]));
    }
}

// ---------------- node-interleaved gathers (20 loads in flight per wave) -----
// wide: stride-64 rows, lane = channel; batch-4 per node x 5 nodes per round
template <bool L>
__device__ __forceinline__ void gather_w5(
    const char* __restrict__ tb, const int2* ls_pr, const int2* __restrict__ g_pr,
    const int (&rbj)[NPW], const int (&dgj)[NPW], int rmax, int lane4,
    float (&agg)[NPW])
{
#pragma unroll
    for (int j = 0; j < NPW; j++) agg[j] = 0.f;
#pragma unroll 1
    for (int r = 0; r < rmax; r += 4) {
        int2 p[NPW][4];
        float v[NPW][4];
#pragma unroll
        for (int j = 0; j < NPW; j++)
#pragma unroll
            for (int u = 0; u < 4; u++) {
                int idx = r + u;
                int ii = (idx < dgj[j]) ? (rbj[j] + idx) : rbj[j];
                p[j][u] = L ? ls_pr[ii] : g_pr[ii];
            }
#pragma unroll
        for (int j = 0; j < NPW; j++)
#pragma unroll
            for (int u = 0; u < 4; u++)
                v[j][u] = *(const float*)(tb + (unsigned)p[j][u].x + lane4);
#pragma unroll
        for (int j = 0; j < NPW; j++)
#pragma unroll
            for (int u = 0; u < 4; u++) {
                float w = (r + u < dgj[j]) ? __int_as_float(p[j][u].y) : 0.f;
                agg[j] = fmaf(w, v[j][u], agg[j]);
            }
    }
}

// narrow: stride-4 rows, lane = (eo, lc), 16 edges/instr; interleave 5 nodes
template <bool L>
__device__ __forceinline__ void gather_n5(
    const char* __restrict__ tb, const int2* ls_pr, const int2* __restrict__ g_pr,
    const int (&rbj)[NPW], const int (&dgj)[NPW], int rmax, int lc4, int eo,
    float (&agg)[NPW])
{
#pragma unroll
    for (int j = 0; j < NPW; j++) agg[j] = 0.f;
#pragma unroll 1
    for (int r = eo; r < rmax; r += 16) {
        int2 p[NPW];
        float v[NPW];
#pragma unroll
        for (int j = 0; j < NPW; j++) {
            int ii = (r < dgj[j]) ? (rbj[j] + r) : rbj[j];
            p[j] = L ? ls_pr[ii] : g_pr[ii];
        }
#pragma unroll
        for (int j = 0; j < NPW; j++)
            v[j] = *(const float*)(tb + ((unsigned)p[j].x >> 4) + lc4);
#pragma unroll
        for (int j = 0; j < NPW; j++) {
            float w = (r < dgj[j]) ? __int_as_float(p[j].y) : 0.f;
            agg[j] = fmaf(w, v[j], agg[j]);
        }
    }
#pragma unroll
    for (int j = 0; j < NPW; j++) {
        agg[j] += __shfl_xor(agg[j], 4);
        agg[j] += __shfl_xor(agg[j], 8);
        agg[j] += __shfl_xor(agg[j], 16);
        agg[j] += __shfl_xor(agg[j], 32);
    }
}

// ---------------- dense: acc(lane=o) += sum_c t2(c) * W[c][o] ----------------
template <int CI, int CO>
__device__ __forceinline__ void dense_step(float (&acc)[NPW], const float (&t2v)[NPW],
                                           const float* lsW, int lane)
{
#pragma unroll
    for (int c = 0; c < CI; c++) {
        float wv = lsW[c * CO + lane];
#pragma unroll
        for (int j = 0; j < NPW; j++)
            acc[j] = fmaf(__shfl(t2v[j], c), wv, acc[j]);
    }
}

__device__ __forceinline__ void stage_w(const float* __restrict__ Wg, float* lsW, int cnt) {
    for (int i = threadIdx.x; i < cnt; i += BLOCK) lsW[i] = Wg[i];
}

// ---------------- one ChebConv layer ----------------
template <int CI, int CO, int K, int ACT, bool PUB>
__device__ void run_layer(
    float (&t1r)[NPW], int& bstep,
    const float* __restrict__ Wg, const float* __restrict__ bg,
    const float* __restrict__ hprev,
    float* tb0, float* tb1, float* __restrict__ hout,
    const int (&nodes)[NPW], const int (&rbj)[NPW], const int (&dgj)[NPW], int rmax,
    bool use_lds, const int2* ls_pr, const int2* __restrict__ g_pr,
    float (*lsWb)[4096], int* bar, int bid, int lane)
{
    float t0r[NPW], acc[NPW];
    // ---- k = 0 ----
    stage_w(Wg, lsWb[0], CI * CO);
    float bv = (bg != nullptr && lane < CO) ? bg[lane] : 0.f;
    __syncthreads();
#pragma unroll
    for (int j = 0; j < NPW; j++) { acc[j] = bv; t0r[j] = t1r[j]; }
    dense_step<CI, CO>(acc, t1r, lsWb[0], lane);
    if (K > 1) stage_w(Wg + CI * CO, lsWb[1], CI * CO);  // prefetch W1

    float* tb[2] = {tb0, tb1};
    int cur = 1;
    int eo = lane >> 2, lc4 = (lane & 3) * 4, lane4 = lane * 4;

#pragma unroll 1
    for (int k = 1; k < K; k++) {
        const char* gs = (const char*)((k == 1) ? hprev : tb[cur]);
        float agg[NPW];
        if (CI == 4) {
            if (use_lds) gather_n5<true >(gs, ls_pr, g_pr, rbj, dgj, rmax, lc4, eo, agg);
            else         gather_n5<false>(gs, ls_pr, g_pr, rbj, dgj, rmax, lc4, eo, agg);
        } else {
            if (use_lds) gather_w5<true >(gs, ls_pr, g_pr, rbj, dgj, rmax, lane4, agg);
            else         gather_w5<false>(gs, ls_pr, g_pr, rbj, dgj, rmax, lane4, agg);
        }
        float t2v[NPW];
#pragma unroll
        for (int j = 0; j < NPW; j++) {
            float t2 = (k == 1) ? agg[j] : fmaf(2.f, agg[j], -t0r[j]);
            if (CI != 4 && lane >= CI) t2 = 0.f;
            t2v[j] = t2;
        }
        if (k < K - 1) {  // publish early; WT stores fly under dense
            float* gd = tb[cur ^ 1];
#pragma unroll
            for (int j = 0; j < NPW; j++) {
                if (CI == 4) {
                    if (lane < 4) ast(&gd[nodes[j] * 4 + lane], t2v[j]);
                } else {
                    ast(&gd[nodes[j] * 64 + lane], t2v[j]);
                }
            }
        }
        __syncthreads();   // lsWb[k&1] staged (prev step) now visible
        dense_step<CI, CO>(acc, t2v, lsWb[k & 1], lane);
        if (k + 1 < K) stage_w(Wg + (size_t)(k + 1) * CI * CO, lsWb[(k + 1) & 1], CI * CO);
#pragma unroll
        for (int j = 0; j < NPW; j++) { t0r[j] = t1r[j]; t1r[j] = t2v[j]; }
        if (k < K - 1) { cur ^= 1; gbar(bar, bstep++, bid); }
    }
    // ---- epilogue ----
#pragma unroll
    for (int j = 0; j < NPW; j++) {
        float a = acc[j];
        float h = (ACT == 1) ? a / (1.f + expf(-a)) : a;
        if (lane >= CO) h = 0.f;
        t1r[j] = h;
    }
    if (PUB) {
#pragma unroll
        for (int j = 0; j < NPW; j++) ast(&hout[nodes[j] * 64 + lane], t1r[j]);
        gbar(bar, bstep++, bid);
    }
}

// ---------------- persistent kernel: all 4 layers, 256 tree barriers ----------
__global__ __launch_bounds__(BLOCK, 2) void persistent(
    const float* __restrict__ x,
    const int* __restrict__ rowptr, const int2* __restrict__ g_pr,
    const float* __restrict__ W1, const float* __restrict__ b1,
    const float* __restrict__ W2, const float* __restrict__ b2,
    const float* __restrict__ W3, const float* __restrict__ b3,
    const float* __restrict__ W4,
    float* t4a, float* t4b, float* tba, float* tbb,
    float* h1, float* h2, float* out, int* bar)
{
    __shared__ int2  ls_pr[ECAP];     // 16 KB CSR slice
    __shared__ float lsWb[2][4096];   // 32 KB double-buffered Wk

    int tid = threadIdx.x;
    int w = tid >> 6, lane = tid & 63;
    int bid = blockIdx.x;

    int nb0 = bid * NPB;
    int eb = rowptr[nb0];
    int ee = rowptr[nb0 + NPB];
    int ecnt = ee - eb;
    bool use_lds = (ecnt <= ECAP);
    if (use_lds) {
        for (int i = tid; i < ecnt; i += BLOCK) ls_pr[i] = g_pr[eb + i];
    }

    int nodes[NPW], rbj[NPW], dgj[NPW];
    int node0 = nb0 + w * NPW;
    int rmax = 0;
#pragma unroll
    for (int j = 0; j < NPW; j++) {
        nodes[j] = node0 + j;
        int r0 = rowptr[nodes[j]], r1 = rowptr[nodes[j] + 1];
        dgj[j] = r1 - r0;
        rbj[j] = use_lds ? (r0 - eb) : r0;
        rmax = max(rmax, dgj[j]);
    }
    __syncthreads();

    float t1r[NPW];
#pragma unroll
    for (int j = 0; j < NPW; j++) t1r[j] = x[nodes[j] * 4 + (lane & 3)];

    int bstep = 0;

    // Layer 1: K=120, 4->64, silu
    run_layer<4, 64, 120, 1, true>(t1r, bstep, W1, b1, x, t4a, t4b, h1,
                                   nodes, rbj, dgj, rmax, use_lds, ls_pr, g_pr,
                                   lsWb, bar, bid, lane);
    // Layer 2: K=120, 64->60, silu
    run_layer<64, 60, 120, 1, true>(t1r, bstep, W2, b2, h1, tba, tbb, h2,
                                    nodes, rbj, dgj, rmax, use_lds, ls_pr, g_pr,
                                    lsWb, bar, bid, lane);
    // Layer 3: K=20, 60->30, silu (output stays in registers)
    run_layer<60, 30, 20, 1, false>(t1r, bstep, W3, b3, h2, tba, tbb, nullptr,
                                    nodes, rbj, dgj, rmax, use_lds, ls_pr, g_pr,
                                    lsWb, bar, bid, lane);

    // Layer 4: K=1, 30->1, sigmoid
    float w4 = (lane < 30) ? W4[lane] : 0.f;
#pragma unroll
    for (int j = 0; j < NPW; j++) {
        float p = t1r[j] * w4;
        p += __shfl_xor(p, 1);
        p += __shfl_xor(p, 2);
        p += __shfl_xor(p, 4);
        p += __shfl_xor(p, 8);
        p += __shfl_xor(p, 16);
        p += __shfl_xor(p, 32);
        if (lane == 0) out[nodes[j]] = 1.f / (1.f + expf(-p));
    }
}

// ---------------- host ----------------
extern "C" void kernel_launch(void* const* d_in, const int* in_sizes, int n_in,
                              void* d_out, int out_size, void* d_ws, size_t ws_size,
                              hipStream_t stream) {
    const float* x  = (const float*)d_in[0];
    const int*   ei = (const int*)d_in[1];
    const float* ew = (const float*)d_in[2];
    const float* W1 = (const float*)d_in[3];
    const float* b1 = (const float*)d_in[4];
    const float* W2 = (const float*)d_in[5];
    const float* b2 = (const float*)d_in[6];
    const float* W3 = (const float*)d_in[7];
    const float* b3 = (const float*)d_in[8];
    const float* W4 = (const float*)d_in[9];
    float* out = (float*)d_out;

    const int n = N_NODES, E = N_EDGES;

    char* ws = (char*)d_ws;
    size_t off = 0;
    auto alloc = [&](size_t bytes) -> void* {
        void* p = ws + off;
        off += (bytes + 255) & ~(size_t)255;
        return p;
    };
    float* deg    = (float*)alloc(n * 4);
    int*   cnt    = (int*)alloc(n * 4);
    int*   fill   = (int*)alloc(n * 4);
    int*   rowptr = (int*)alloc((n + 4) * 4);
    float* normw  = (float*)alloc((size_t)E * 4);
    int2*  pr     = (int2*)alloc((size_t)E * 8);
    int*   bar    = (int*)alloc(1024 * 4);
    float* t4a = (float*)alloc(n * 4 * 4);
    float* t4b = (float*)alloc(n * 4 * 4);
    float* tba = (float*)alloc(n * 64 * 4);
    float* tbb = (float*)alloc(n * 64 * 4);
    float* h1  = (float*)alloc(n * 64 * 4);
    float* h2  = (float*)alloc(n * 64 * 4);
    (void)ws_size; (void)n_in; (void)in_sizes; (void)out_size;

    k_init<<<(n + 255) / 256, 256, 0, stream>>>(deg, cnt, fill, bar, n);
    k_deg <<<(E + 255) / 256, 256, 0, stream>>>(ei, ew, deg, E);
    k_dis <<<(n + 255) / 256, 256, 0, stream>>>(deg, n);
    k_norm<<<(E + 255) / 256, 256, 0, stream>>>(ei, ew, deg, normw, cnt, E);
    k_scan<<<1, 1024, 0, stream>>>(cnt, rowptr, n);
    k_fill<<<(E + 255) / 256, 256, 0, stream>>>(ei, normw, rowptr, fill, pr, E);

    persistent<<<GRID, BLOCK, 0, stream>>>(
        x, rowptr, pr,
        W1, b1, W2, b2, W3, b3, W4,
        t4a, t4b, tba, tbb, h1, h2, out, bar);
}